// Round 1
// baseline (4123.759 us; speedup 1.0000x reference)
//
#include <hip/hip_runtime.h>

#define B_DIM 64
#define T_DIM 2048
#define F_DIM 512
#define H_DIM 128
#define G_DIM 384  // 3*H

__device__ __forceinline__ float sigmoid_f(float x) {
    return __fdividef(1.0f, 1.0f + __expf(-x));
}
__device__ __forceinline__ float tanh_f(float x) {
    return __fdividef(2.0f, 1.0f + __expf(-2.0f * x)) - 1.0f;
}

// C[M x NDIM] = A[M x KDIM] @ W[NDIM x KDIM]^T + bias
// If DO_LEN: also count rows with nonzero sum per batch (T_DIM rows/batch) into lengths[b].
template<int KDIM, int NDIM, bool DO_LEN>
__global__ __launch_bounds__(256)
void gemm_bias_kernel(const float* __restrict__ A, const float* __restrict__ W,
                      const float* __restrict__ bias, float* __restrict__ C,
                      int* __restrict__ lengths)
{
    constexpr int KC = 16;
    constexpr int NB = NDIM / 128;   // n-blocks of 128
    constexpr int WQ = NDIM / 64;    // W float4 stage loads per thread per chunk
    constexpr int PA = 68;           // At row pitch (floats), padded
    constexpr int PW = NDIM + 4;     // Wt row pitch
    __shared__ __align__(16) float At[KC * PA];
    __shared__ __align__(16) float Wt[KC * PW];

    const int tid = threadIdx.x;
    const int gm  = blockIdx.x * 64;     // first row of this block's tile
    const int tn  = tid & 31;            // n-group 0..31
    const int tm  = tid >> 5;            // m-group 0..7
    const int m0  = tm * 8;
    const int arow = tid >> 2;           // staging: row 0..63
    const int akq  = tid & 3;            // staging: k-quad 0..3

    const float* Arow = A + (size_t)(gm + arow) * KDIM + akq * 4;
    float4 aPre = *(const float4*)(Arow);
    float4 wPre[WQ];
    int wn_[WQ], wkq_[WQ];
#pragma unroll
    for (int q = 0; q < WQ; ++q) {
        int idx = tid + q * 256;
        wn_[q]  = idx >> 2;
        wkq_[q] = idx & 3;
        wPre[q] = *(const float4*)(W + (size_t)wn_[q] * KDIM + wkq_[q] * 4);
    }

    float acc[NB][8][4];
#pragma unroll
    for (int bb = 0; bb < NB; ++bb)
#pragma unroll
        for (int mm = 0; mm < 8; ++mm)
#pragma unroll
            for (int c = 0; c < 4; ++c) acc[bb][mm][c] = 0.0f;

    float rowsum = 0.0f;

    for (int kc = 0; kc < KDIM; kc += KC) {
        if (DO_LEN) rowsum += aPre.x + aPre.y + aPre.z + aPre.w;
        At[(akq*4+0)*PA + arow] = aPre.x;
        At[(akq*4+1)*PA + arow] = aPre.y;
        At[(akq*4+2)*PA + arow] = aPre.z;
        At[(akq*4+3)*PA + arow] = aPre.w;
#pragma unroll
        for (int q = 0; q < WQ; ++q) {
            Wt[(wkq_[q]*4+0)*PW + wn_[q]] = wPre[q].x;
            Wt[(wkq_[q]*4+1)*PW + wn_[q]] = wPre[q].y;
            Wt[(wkq_[q]*4+2)*PW + wn_[q]] = wPre[q].z;
            Wt[(wkq_[q]*4+3)*PW + wn_[q]] = wPre[q].w;
        }
        __syncthreads();
        if (kc + KC < KDIM) {   // prefetch next chunk while computing this one
            aPre = *(const float4*)(Arow + kc + KC);
#pragma unroll
            for (int q = 0; q < WQ; ++q)
                wPre[q] = *(const float4*)(W + (size_t)wn_[q] * KDIM + kc + KC + wkq_[q] * 4);
        }
#pragma unroll
        for (int k = 0; k < KC; ++k) {
            float4 a0 = *(const float4*)&At[k*PA + m0];
            float4 a1 = *(const float4*)&At[k*PA + m0 + 4];
            float av[8] = {a0.x, a0.y, a0.z, a0.w, a1.x, a1.y, a1.z, a1.w};
#pragma unroll
            for (int bb = 0; bb < NB; ++bb) {
                float4 w4 = *(const float4*)&Wt[k*PW + bb*128 + tn*4];
#pragma unroll
                for (int mm = 0; mm < 8; ++mm) {
                    acc[bb][mm][0] = fmaf(av[mm], w4.x, acc[bb][mm][0]);
                    acc[bb][mm][1] = fmaf(av[mm], w4.y, acc[bb][mm][1]);
                    acc[bb][mm][2] = fmaf(av[mm], w4.z, acc[bb][mm][2]);
                    acc[bb][mm][3] = fmaf(av[mm], w4.w, acc[bb][mm][3]);
                }
            }
        }
        __syncthreads();
    }

#pragma unroll
    for (int bb = 0; bb < NB; ++bb) {
        float4 b4 = *(const float4*)&bias[bb*128 + tn*4];
#pragma unroll
        for (int mm = 0; mm < 8; ++mm) {
            float4 o;
            o.x = acc[bb][mm][0] + b4.x;
            o.y = acc[bb][mm][1] + b4.y;
            o.z = acc[bb][mm][2] + b4.z;
            o.w = acc[bb][mm][3] + b4.w;
            *(float4*)&C[(size_t)(gm + m0 + mm) * NDIM + bb*128 + tn*4] = o;
        }
    }

    if (DO_LEN) {
        // threads akq=0..3 share the same row; reduce their partial sums
        rowsum += __shfl_xor(rowsum, 1);
        rowsum += __shfl_xor(rowsum, 2);
        if (akq == 0 && rowsum != 0.0f)
            atomicAdd(&lengths[(gm + arow) >> 11], 1);   // row / T_DIM
    }
}

// One workgroup per batch element. 512 threads: thread (jj = tid&127, kh = tid>>7)
// holds W_hh rows {jj, jj+128, jj+256} restricted to k in [kh*32, kh*32+32) in VGPRs.
// Per step: partial matvecs -> LDS -> barrier -> 128 threads combine gates -> barrier.
template<bool WRITE_SEQ>
__global__ __launch_bounds__(512)
void gru_scan_kernel(const float* __restrict__ gx,    // [B,T,3H] (includes b_ih)
                     const float* __restrict__ whh,   // [3H,H] this layer
                     const float* __restrict__ bhh,   // [3H]
                     const int*   __restrict__ lengths,
                     float* __restrict__ seq_out,     // [B,T,H] if WRITE_SEQ
                     float* __restrict__ final_out)   // [B,H]  if !WRITE_SEQ
{
    const int b   = blockIdx.x;
    const int tid = threadIdx.x;
    const int jj  = tid & 127;
    const int kh  = tid >> 7;   // 0..3

    __shared__ __align__(16) float h_lds[H_DIM];
    __shared__ __align__(16) float part[4 * H_DIM * 4];  // [kh][jj][{r,z,n,pad}]

    // resident weights: 96 VGPRs/thread
    float wr_[32], wz_[32], wn_[32];
    {
        const float* wp = whh + (size_t)jj * H_DIM + kh * 32;
#pragma unroll
        for (int q = 0; q < 8; ++q) {
            float4 v0 = *(const float4*)(wp + q*4);            // gate r: row jj
            float4 v1 = *(const float4*)(wp + 16384 + q*4);    // gate z: row jj+128
            float4 v2 = *(const float4*)(wp + 32768 + q*4);    // gate n: row jj+256
            wr_[q*4+0]=v0.x; wr_[q*4+1]=v0.y; wr_[q*4+2]=v0.z; wr_[q*4+3]=v0.w;
            wz_[q*4+0]=v1.x; wz_[q*4+1]=v1.y; wz_[q*4+2]=v1.z; wz_[q*4+3]=v1.w;
            wn_[q*4+0]=v2.x; wn_[q*4+1]=v2.y; wn_[q*4+2]=v2.z; wn_[q*4+3]=v2.w;
        }
    }

    const int len = lengths[b];
    const float* gxb = gx + (size_t)b * T_DIM * G_DIM;
    float* seqb = WRITE_SEQ ? (seq_out + (size_t)b * T_DIM * H_DIM) : nullptr;

    float h_reg = 0.0f, bhr = 0.0f, bhz = 0.0f, bhn = 0.0f;
    // ping-pong gx prefetch buffers (even/odd steps), 2 steps ahead
    float exr=0,exz=0,exn=0, oxr=0,oxz=0,oxn=0;
    if (tid < H_DIM) {
        h_lds[tid] = 0.0f;
        bhr = bhh[jj]; bhz = bhh[jj+128]; bhn = bhh[jj+256];
        exr = gxb[jj];           exz = gxb[jj+128];           exn = gxb[jj+256];
        oxr = gxb[G_DIM+jj];     oxz = gxb[G_DIM+jj+128];     oxn = gxb[G_DIM+jj+256];
    }
    __syncthreads();

    const float* hb = h_lds + kh * 32;
    float* pp = &part[(kh*128 + jj)*4];

    auto step = [&](int t, float& cxr, float& cxz, float& cxn) {
        float ar = 0.0f, az = 0.0f, an = 0.0f;
#pragma unroll
        for (int q = 0; q < 8; ++q) {
            float4 h4 = *(const float4*)(hb + q*4);   // wave-uniform broadcast read
            float hv[4] = {h4.x, h4.y, h4.z, h4.w};
#pragma unroll
            for (int u = 0; u < 4; ++u) {
                ar = fmaf(wr_[q*4+u], hv[u], ar);
                az = fmaf(wz_[q*4+u], hv[u], az);
                an = fmaf(wn_[q*4+u], hv[u], an);
            }
        }
        *(float4*)pp = make_float4(ar, az, an, 0.0f);
        __syncthreads();
        if (tid < H_DIM) {
            const float4 p0 = *(const float4*)&part[(0*128 + jj)*4];
            const float4 p1 = *(const float4*)&part[(1*128 + jj)*4];
            const float4 p2 = *(const float4*)&part[(2*128 + jj)*4];
            const float4 p3 = *(const float4*)&part[(3*128 + jj)*4];
            float hr = p0.x + p1.x + p2.x + p3.x + bhr;
            float hz = p0.y + p1.y + p2.y + p3.y + bhz;
            float hn = p0.z + p1.z + p2.z + p3.z + bhn;
            // prefetch gx for t+2 into this parity's buffer (consumed 2 steps later)
            int tp = t + 2; if (tp > T_DIM - 1) tp = T_DIM - 1;
            const float* gp = gxb + (size_t)tp * G_DIM + jj;
            float nxr = gp[0], nxz = gp[128], nxn = gp[256];
            float r  = sigmoid_f(cxr + hr);
            float z  = sigmoid_f(cxz + hz);
            float nn = tanh_f(cxn + r * hn);
            float hnew = nn + z * (h_reg - nn);   // (1-z)*n + z*h
            h_reg = hnew;
            h_lds[jj] = hnew;
            if (WRITE_SEQ) seqb[(size_t)t * H_DIM + jj] = hnew;
            cxr = nxr; cxz = nxz; cxn = nxn;
        }
        __syncthreads();
    };

    int t = 0;
    while (t < len) {            // len is block-uniform; barriers stay uniform
        step(t, exr, exz, exn);
        ++t;
        if (t >= len) break;
        step(t, oxr, oxz, oxn);
        ++t;
    }

    if (!WRITE_SEQ && tid < H_DIM)
        final_out[(size_t)b * H_DIM + jj] = h_reg;
}

extern "C" void kernel_launch(void* const* d_in, const int* in_sizes, int n_in,
                              void* d_out, int out_size, void* d_ws, size_t ws_size,
                              hipStream_t stream)
{
    (void)in_sizes; (void)n_in; (void)out_size; (void)ws_size;
    const float* x      = (const float*)d_in[0];
    const float* w_proj = (const float*)d_in[1];
    const float* b_proj = (const float*)d_in[2];
    const float* w_ih   = (const float*)d_in[3];
    const float* w_hh   = (const float*)d_in[4];
    const float* b_ih   = (const float*)d_in[5];
    const float* b_hh   = (const float*)d_in[6];
    float* out = (float*)d_out;

    // ws layout: [0,64MB) feat (layer input, later overwritten by layer-0 output);
    //            [64MB,256MB) gx (reused for both layers); [256MB,+256B) lengths
    char*  ws      = (char*)d_ws;
    float* feat    = (float*)(ws);
    float* gxbuf   = (float*)(ws + 67108864ull);
    int*   lengths = (int*)  (ws + 268435456ull);

    hipMemsetAsync(lengths, 0, B_DIM * sizeof(int), stream);

    const int M = B_DIM * T_DIM;
    // 1) feat = x @ w_proj^T + b_proj   (+ ragged lengths from row sums)
    gemm_bias_kernel<F_DIM, H_DIM, true><<<M/64, 256, 0, stream>>>(x, w_proj, b_proj, feat, lengths);
    // 2) gx0 = feat @ w_ih[0]^T + b_ih[0]
    gemm_bias_kernel<H_DIM, G_DIM, false><<<M/64, 256, 0, stream>>>(feat, w_ih, b_ih, gxbuf, nullptr);
    // 3) layer-0 scan -> out0 (overwrites feat; rows t>=len stay as stale feat, unused downstream)
    gru_scan_kernel<true><<<B_DIM, 512, 0, stream>>>(gxbuf, w_hh, b_hh, lengths, feat, nullptr);
    // 4) gx1 = out0 @ w_ih[1]^T + b_ih[1]
    gemm_bias_kernel<H_DIM, G_DIM, false><<<M/64, 256, 0, stream>>>(feat, w_ih + G_DIM*H_DIM, b_ih + G_DIM, gxbuf, nullptr);
    // 5) layer-1 scan -> final top-layer state
    gru_scan_kernel<false><<<B_DIM, 512, 0, stream>>>(gxbuf, w_hh + G_DIM*H_DIM, b_hh + G_DIM, lengths, nullptr, out);
}

// Round 2
// 3803.601 us; speedup vs baseline: 1.0842x; 1.0842x over previous
//
#include <hip/hip_runtime.h>

#define B_DIM 64
#define T_DIM 2048
#define F_DIM 512
#define H_DIM 128
#define G_DIM 384  // 3*H

__device__ __forceinline__ float sigmoid_f(float x) {
    return __fdividef(1.0f, 1.0f + __expf(-x));
}
__device__ __forceinline__ float tanh_f(float x) {
    return __fdividef(2.0f, 1.0f + __expf(-2.0f * x)) - 1.0f;
}

// C[M x NDIM] = A[M x KDIM] @ W[NDIM x KDIM]^T + bias
// If DO_LEN: also count rows with nonzero sum per batch (T_DIM rows/batch) into lengths[b].
template<int KDIM, int NDIM, bool DO_LEN>
__global__ __launch_bounds__(256)
void gemm_bias_kernel(const float* __restrict__ A, const float* __restrict__ W,
                      const float* __restrict__ bias, float* __restrict__ C,
                      int* __restrict__ lengths)
{
    constexpr int KC = 16;
    constexpr int NB = NDIM / 128;   // n-blocks of 128
    constexpr int WQ = NDIM / 64;    // W float4 stage loads per thread per chunk
    constexpr int PA = 68;           // At row pitch (floats), padded
    constexpr int PW = NDIM + 4;     // Wt row pitch
    __shared__ __align__(16) float At[KC * PA];
    __shared__ __align__(16) float Wt[KC * PW];

    const int tid = threadIdx.x;
    const int gm  = blockIdx.x * 64;     // first row of this block's tile
    const int tn  = tid & 31;            // n-group 0..31
    const int tm  = tid >> 5;            // m-group 0..7
    const int m0  = tm * 8;
    const int arow = tid >> 2;           // staging: row 0..63
    const int akq  = tid & 3;            // staging: k-quad 0..3

    const float* Arow = A + (size_t)(gm + arow) * KDIM + akq * 4;
    float4 aPre = *(const float4*)(Arow);
    float4 wPre[WQ];
    int wn_[WQ], wkq_[WQ];
#pragma unroll
    for (int q = 0; q < WQ; ++q) {
        int idx = tid + q * 256;
        wn_[q]  = idx >> 2;
        wkq_[q] = idx & 3;
        wPre[q] = *(const float4*)(W + (size_t)wn_[q] * KDIM + wkq_[q] * 4);
    }

    float acc[NB][8][4];
#pragma unroll
    for (int bb = 0; bb < NB; ++bb)
#pragma unroll
        for (int mm = 0; mm < 8; ++mm)
#pragma unroll
            for (int c = 0; c < 4; ++c) acc[bb][mm][c] = 0.0f;

    float rowsum = 0.0f;

    for (int kc = 0; kc < KDIM; kc += KC) {
        if (DO_LEN) rowsum += aPre.x + aPre.y + aPre.z + aPre.w;
        At[(akq*4+0)*PA + arow] = aPre.x;
        At[(akq*4+1)*PA + arow] = aPre.y;
        At[(akq*4+2)*PA + arow] = aPre.z;
        At[(akq*4+3)*PA + arow] = aPre.w;
#pragma unroll
        for (int q = 0; q < WQ; ++q) {
            Wt[(wkq_[q]*4+0)*PW + wn_[q]] = wPre[q].x;
            Wt[(wkq_[q]*4+1)*PW + wn_[q]] = wPre[q].y;
            Wt[(wkq_[q]*4+2)*PW + wn_[q]] = wPre[q].z;
            Wt[(wkq_[q]*4+3)*PW + wn_[q]] = wPre[q].w;
        }
        __syncthreads();
        if (kc + KC < KDIM) {   // prefetch next chunk while computing this one
            aPre = *(const float4*)(Arow + kc + KC);
#pragma unroll
            for (int q = 0; q < WQ; ++q)
                wPre[q] = *(const float4*)(W + (size_t)wn_[q] * KDIM + kc + KC + wkq_[q] * 4);
        }
#pragma unroll
        for (int k = 0; k < KC; ++k) {
            float4 a0 = *(const float4*)&At[k*PA + m0];
            float4 a1 = *(const float4*)&At[k*PA + m0 + 4];
            float av[8] = {a0.x, a0.y, a0.z, a0.w, a1.x, a1.y, a1.z, a1.w};
#pragma unroll
            for (int bb = 0; bb < NB; ++bb) {
                float4 w4 = *(const float4*)&Wt[k*PW + bb*128 + tn*4];
#pragma unroll
                for (int mm = 0; mm < 8; ++mm) {
                    acc[bb][mm][0] = fmaf(av[mm], w4.x, acc[bb][mm][0]);
                    acc[bb][mm][1] = fmaf(av[mm], w4.y, acc[bb][mm][1]);
                    acc[bb][mm][2] = fmaf(av[mm], w4.z, acc[bb][mm][2]);
                    acc[bb][mm][3] = fmaf(av[mm], w4.w, acc[bb][mm][3]);
                }
            }
        }
        __syncthreads();
    }

#pragma unroll
    for (int bb = 0; bb < NB; ++bb) {
        float4 b4 = *(const float4*)&bias[bb*128 + tn*4];
#pragma unroll
        for (int mm = 0; mm < 8; ++mm) {
            float4 o;
            o.x = acc[bb][mm][0] + b4.x;
            o.y = acc[bb][mm][1] + b4.y;
            o.z = acc[bb][mm][2] + b4.z;
            o.w = acc[bb][mm][3] + b4.w;
            *(float4*)&C[(size_t)(gm + m0 + mm) * NDIM + bb*128 + tn*4] = o;
        }
    }

    if (DO_LEN) {
        // threads akq=0..3 share the same row; reduce their partial sums
        rowsum += __shfl_xor(rowsum, 1);
        rowsum += __shfl_xor(rowsum, 2);
        if (akq == 0 && rowsum != 0.0f)
            atomicAdd(&lengths[(gm + arow) >> 11], 1);   // row / T_DIM
    }
}

// One workgroup per batch element. 512 threads: thread (jj = tid>>2, kq = tid&3)
// holds W_hh rows {jj, jj+128, jj+256} for k in [kq*32, kq*32+32) in 96 VGPRs.
// Per step: 8x ds_read_b128 from bank-shifted h replicas (conflict-free) -> 96 FMA
// -> quad shfl_xor reduce (in-register, no LDS) -> all 4 lanes compute gates
// redundantly -> each lane writes its replica of h into the OTHER buffer
// (double-buffered: no WAR race) -> ONE __syncthreads per step.
template<bool WRITE_SEQ>
__global__ __launch_bounds__(512, 2)
void gru_scan_kernel(const float* __restrict__ gx,    // [B,T,3H] (includes b_ih)
                     const float* __restrict__ whh,   // [3H,H] this layer
                     const float* __restrict__ bhh,   // [3H]
                     const int*   __restrict__ lengths,
                     float* __restrict__ seq_out,     // [B,T,H] if WRITE_SEQ
                     float* __restrict__ final_out)   // [B,H]  if !WRITE_SEQ
{
    constexpr int HP = 136;  // replica pitch (floats): replica kq bank-shifted by kq*8
    __shared__ __align__(16) float h_rep[2][4 * HP];

    const int b   = blockIdx.x;
    const int tid = threadIdx.x;
    const int jj  = tid >> 2;   // 0..127 output element
    const int kq  = tid & 3;    // 0..3  k-quarter

    // resident weights: 96 VGPRs/thread
    float wr_[32], wz_[32], wn_[32];
    {
        const float* wp = whh + (size_t)jj * H_DIM + kq * 32;
#pragma unroll
        for (int q = 0; q < 8; ++q) {
            float4 v0 = *(const float4*)(wp + q*4);            // gate r: row jj
            float4 v1 = *(const float4*)(wp + 16384 + q*4);    // gate z: row jj+128
            float4 v2 = *(const float4*)(wp + 32768 + q*4);    // gate n: row jj+256
            wr_[4*q+0]=v0.x; wr_[4*q+1]=v0.y; wr_[4*q+2]=v0.z; wr_[4*q+3]=v0.w;
            wz_[4*q+0]=v1.x; wz_[4*q+1]=v1.y; wz_[4*q+2]=v1.z; wz_[4*q+3]=v1.w;
            wn_[4*q+0]=v2.x; wn_[4*q+1]=v2.y; wn_[4*q+2]=v2.z; wn_[4*q+3]=v2.w;
        }
    }

    const int len = lengths[b];
    const float* gxb = gx + (size_t)b * T_DIM * G_DIM;
    float* seqb = WRITE_SEQ ? (seq_out + (size_t)b * T_DIM * H_DIM) : nullptr;

    const float bhr = bhh[jj], bhz = bhh[jj + 128], bhn = bhh[jj + 256];

    for (int i = tid; i < 2 * 4 * HP; i += 512) ((float*)h_rep)[i] = 0.0f;

    // ping-pong gx prefetch (even/odd steps), 2 steps ahead; 4 kq lanes redundant
    float exr = gxb[jj],         exz = gxb[jj + 128],         exn = gxb[jj + 256];
    float oxr = gxb[G_DIM + jj], oxz = gxb[G_DIM + jj + 128], oxn = gxb[G_DIM + jj + 256];
    __syncthreads();

    float h_prev = 0.0f;                      // h[jj], identical across the 4 kq lanes
    const int rdoff = kq * HP + kq * 32;      // read base within a buffer
    const int wroff = kq * HP + jj;           // write slot within a buffer

    auto step = [&](int t, int pr, float& cxr, float& cxz, float& cxn) {
        const float* hb = &h_rep[pr][rdoff];
        float ar = 0.0f, az = 0.0f, an = 0.0f;
#pragma unroll
        for (int q = 0; q < 8; ++q) {
            float4 h4 = *(const float4*)(hb + 4*q);   // 4 bank-disjoint addrs, 16-lane bcast
            ar = fmaf(wr_[4*q+0], h4.x, ar); ar = fmaf(wr_[4*q+1], h4.y, ar);
            ar = fmaf(wr_[4*q+2], h4.z, ar); ar = fmaf(wr_[4*q+3], h4.w, ar);
            az = fmaf(wz_[4*q+0], h4.x, az); az = fmaf(wz_[4*q+1], h4.y, az);
            az = fmaf(wz_[4*q+2], h4.z, az); az = fmaf(wz_[4*q+3], h4.w, az);
            an = fmaf(wn_[4*q+0], h4.x, an); an = fmaf(wn_[4*q+1], h4.y, an);
            an = fmaf(wn_[4*q+2], h4.z, an); an = fmaf(wn_[4*q+3], h4.w, an);
        }
        // quad butterfly: after this all 4 kq lanes hold the full k-sum
        ar += __shfl_xor(ar, 1); az += __shfl_xor(az, 1); an += __shfl_xor(an, 1);
        ar += __shfl_xor(ar, 2); az += __shfl_xor(az, 2); an += __shfl_xor(an, 2);
        // prefetch gx for t+2 into this parity's registers
        int tp = t + 2; if (tp > T_DIM - 1) tp = T_DIM - 1;
        const float* gp = gxb + (size_t)tp * G_DIM + jj;
        float nxr = gp[0], nxz = gp[128], nxn = gp[256];
        // gate math, computed redundantly by all 4 lanes (identical values)
        float hr = ar + bhr, hz = az + bhz, hn = an + bhn;
        float r  = sigmoid_f(cxr + hr);
        float z  = sigmoid_f(cxz + hz);
        float nn = tanh_f(cxn + r * hn);
        float hnew = nn + z * (h_prev - nn);   // (1-z)*n + z*h
        h_prev = hnew;
        h_rep[pr ^ 1][wroff] = hnew;           // write own replica into other buffer
        if (WRITE_SEQ && kq == 0) seqb[(size_t)t * H_DIM + jj] = hnew;
        cxr = nxr; cxz = nxz; cxn = nxn;
        __syncthreads();                       // single barrier per step
    };

    int t = 0;
    while (t < len) {            // len is block-uniform; barriers stay uniform
        step(t, 0, exr, exz, exn);
        ++t;
        if (t >= len) break;
        step(t, 1, oxr, oxz, oxn);
        ++t;
    }

    if (!WRITE_SEQ && kq == 0)
        final_out[(size_t)b * H_DIM + jj] = h_prev;
}

extern "C" void kernel_launch(void* const* d_in, const int* in_sizes, int n_in,
                              void* d_out, int out_size, void* d_ws, size_t ws_size,
                              hipStream_t stream)
{
    (void)in_sizes; (void)n_in; (void)out_size; (void)ws_size;
    const float* x      = (const float*)d_in[0];
    const float* w_proj = (const float*)d_in[1];
    const float* b_proj = (const float*)d_in[2];
    const float* w_ih   = (const float*)d_in[3];
    const float* w_hh   = (const float*)d_in[4];
    const float* b_ih   = (const float*)d_in[5];
    const float* b_hh   = (const float*)d_in[6];
    float* out = (float*)d_out;

    // ws layout: [0,64MB) feat (layer input, later overwritten by layer-0 output);
    //            [64MB,256MB) gx (reused for both layers); [256MB,+256B) lengths
    char*  ws      = (char*)d_ws;
    float* feat    = (float*)(ws);
    float* gxbuf   = (float*)(ws + 67108864ull);
    int*   lengths = (int*)  (ws + 268435456ull);

    hipMemsetAsync(lengths, 0, B_DIM * sizeof(int), stream);

    const int M = B_DIM * T_DIM;
    // 1) feat = x @ w_proj^T + b_proj   (+ ragged lengths from row sums)
    gemm_bias_kernel<F_DIM, H_DIM, true><<<M/64, 256, 0, stream>>>(x, w_proj, b_proj, feat, lengths);
    // 2) gx0 = feat @ w_ih[0]^T + b_ih[0]
    gemm_bias_kernel<H_DIM, G_DIM, false><<<M/64, 256, 0, stream>>>(feat, w_ih, b_ih, gxbuf, nullptr);
    // 3) layer-0 scan -> out0 (overwrites feat; rows t>=len stay as stale feat, unused downstream)
    gru_scan_kernel<true><<<B_DIM, 512, 0, stream>>>(gxbuf, w_hh, b_hh, lengths, feat, nullptr);
    // 4) gx1 = out0 @ w_ih[1]^T + b_ih[1]
    gemm_bias_kernel<H_DIM, G_DIM, false><<<M/64, 256, 0, stream>>>(feat, w_ih + G_DIM*H_DIM, b_ih + G_DIM, gxbuf, nullptr);
    // 5) layer-1 scan -> final top-layer state
    gru_scan_kernel<false><<<B_DIM, 512, 0, stream>>>(gxbuf, w_hh + G_DIM*H_DIM, b_hh + G_DIM, lengths, nullptr, out);
}